// Round 10
// baseline (587.148 us; speedup 1.0000x reference)
//
#include <hip/hip_runtime.h>
#include <hip/hip_bf16.h>
#include <stdint.h>

#define NI 256
#define NT 256
#define NL 25
#define NE 128
#define NHW 49
#define NTL (NT*NL)   // 6400

#define WAVES 8            // waves (=images) per match WG
#define CH_T 16            // texts per chunk
#define CH_TILES 25        // 16-row B tiles per chunk

typedef __attribute__((ext_vector_type(8))) short bf16x8;
typedef __attribute__((ext_vector_type(4))) float f32x4;

__device__ __forceinline__ short f2bf(float x) {
    __hip_bfloat16 h = __float2bfloat16(x);
    return *reinterpret_cast<short*>(&h);
}

// ---- prep body (shared by real kernel and x16 probe) ----
__device__ __forceinline__ void prep_body(
    int bid, const float* __restrict__ emb, const int* __restrict__ text,
    const float* __restrict__ img,
    __hip_bfloat16* __restrict__ tf3, __hip_bfloat16* __restrict__ P2,
    float* tile)
{
    if (bid < 400) {
        int idx  = bid * 256 + threadIdx.x;   // 16B chunk id, 102400 total
        int lane = idx & 63;
        int k    = (idx >> 6) & 3;
        int j    = idx >> 8;                  // 0..399
        int lr = lane & 15, lhi = lane >> 4;
        int row = j * 16 + lr;
        int tok = text[row];
        const float* src = emb + (size_t)tok * NE + k * 32 + lhi * 8;
        float4 a = *reinterpret_cast<const float4*>(src);
        float4 b = *reinterpret_cast<const float4*>(src + 4);
        bf16x8 o;
        o[0] = f2bf(a.x); o[1] = f2bf(a.y); o[2] = f2bf(a.z); o[3] = f2bf(a.w);
        o[4] = f2bf(b.x); o[5] = f2bf(b.y); o[6] = f2bf(b.z); o[7] = f2bf(b.w);
        *reinterpret_cast<bf16x8*>(tf3 + (size_t)idx * 8) = o;
    } else {
        int i = bid - 400;
        const float4* src4 = reinterpret_cast<const float4*>(img + (size_t)i * NE * NHW);
        float4* tile4 = reinterpret_cast<float4*>(tile);
        for (int idx = threadIdx.x; idx < NE * NHW / 4; idx += 256) tile4[idx] = src4[idx];
        __syncthreads();
        for (int idx = threadIdx.x; idx < 1024; idx += 256) {   // (mk, lane)
            int mk = idx >> 6, lane = idx & 63;
            int m = mk >> 2, k = mk & 3;
            int lr = lane & 15, lhi = lane >> 4;
            int p = m * 16 + lr;
            bf16x8 o;
            #pragma unroll
            for (int j = 0; j < 8; j++) {
                int e = k * 32 + lhi * 8 + j;
                o[j] = (p < NHW) ? f2bf(tile[e * NHW + p]) : (short)0;
            }
            *reinterpret_cast<bf16x8*>(P2 + ((size_t)(i * 16 + mk) * 64 + lane) * 8) = o;
        }
    }
}

__global__ __launch_bounds__(256) void prep_kernel(
    const float* __restrict__ emb, const int* __restrict__ text,
    const float* __restrict__ img,
    __hip_bfloat16* __restrict__ tf3, __hip_bfloat16* __restrict__ P2)
{
    __shared__ float tile[NE * NHW];
    prep_body(blockIdx.x, emb, text, img, tf3, P2, tile);
}

__global__ __launch_bounds__(256) void prep_probe(
    const float* __restrict__ emb, const int* __restrict__ text,
    const float* __restrict__ img,
    __hip_bfloat16* __restrict__ tf3, __hip_bfloat16* __restrict__ P2)
{
    __shared__ float tile[NE * NHW];
    prep_body(blockIdx.x % 656, emb, text, img, tf3, P2, tile);
}

// ---- Match (template ablation battery; V0 is the real kernel) ----
// V0: full.  V1: no reduce tree (accs asm-kept).  V2: B loaded once
// (no per-tile loads, per-iter pinned).  V3: no MFMA (loads+reduce only).
template<int V>
__global__ __launch_bounds__(512, 4) void match_t(
    const __hip_bfloat16* __restrict__ tf3,
    const __hip_bfloat16* __restrict__ P2,
    const int* __restrict__ text_length,
    const float* __restrict__ logit_scale,
    float* __restrict__ out)
{
    __shared__ float vals[WAVES][CH_TILES][64];   // per-lane 16-patch max

    const int b    = blockIdx.x & 511;
    const int ig   = b & 31;     // image group (8 images)
    const int tq   = b >> 5;     // text chunk (16 texts = 25 tiles)
    const int tid  = threadIdx.x;
    const int wave = tid >> 6;
    const int lane = tid & 63;
    const int lhi  = lane >> 4;

    // pfrag: 16 coalesced 1KB loads from fragment-order P2, pinned resident
    const int img = ig * WAVES + wave;
    const bf16x8* p2 = reinterpret_cast<const bf16x8*>(P2) + (size_t)img * 16 * 64 + lane;
    bf16x8 pfrag[4][4];
    #pragma unroll
    for (int m = 0; m < 4; m++)
        #pragma unroll
        for (int k = 0; k < 4; k++)
            pfrag[m][k] = p2[(m * 4 + k) * 64];
    #pragma unroll
    for (int m = 0; m < 4; m++)
        #pragma unroll
        for (int k = 0; k < 4; k++)
            asm volatile("" : "+v"(pfrag[m][k]));

    // B-fragment stream base: tile j at +j*4096, k at +k*1024, lane*16
    const char* tb = (const char*)tf3 + (size_t)tq * CH_TILES * 4096 + lane * 16;

    auto loadT = [&](bf16x8* T, int j) {
        #pragma unroll
        for (int k = 0; k < 4; k++)
            T[k] = *reinterpret_cast<const bf16x8*>(tb + j * 4096 + k * 1024);
    };

    auto compute = [&](const bf16x8* T, int j) {
        if constexpr (V == 3) {
            // no MFMA: reduce raw T bits (loads + reduce + store skeleton)
            f32x4 f0 = __builtin_bit_cast(f32x4, T[0]);
            f32x4 f1 = __builtin_bit_cast(f32x4, T[1]);
            f32x4 f2 = __builtin_bit_cast(f32x4, T[2]);
            f32x4 f3 = __builtin_bit_cast(f32x4, T[3]);
            float a = fmaxf(fmaxf(f0[0], f0[1]), fmaxf(f0[2], f0[3]));
            float c = fmaxf(fmaxf(f1[0], f1[1]), fmaxf(f1[2], f1[3]));
            float d = fmaxf(fmaxf(f2[0], f2[1]), fmaxf(f2[2], f2[3]));
            float e = fmaxf(fmaxf(f3[0], f3[1]), fmaxf(f3[2], f3[3]));
            float vmax = fmaxf(fmaxf(a, c), (lhi == 0) ? d : fmaxf(d, e));
            vals[wave][j][lane] = vmax;
            return;
        }
        float vmax = -3e38f;
        #pragma unroll
        for (int mh = 0; mh < 2; mh++) {
            f32x4 acc0 = {}, acc1 = {};
            #pragma unroll
            for (int k = 0; k < 4; k++) {
                acc0 = __builtin_amdgcn_mfma_f32_16x16x32_bf16(
                    pfrag[mh * 2][k], T[k], acc0, 0, 0, 0);
                acc1 = __builtin_amdgcn_mfma_f32_16x16x32_bf16(
                    pfrag[mh * 2 + 1][k], T[k], acc1, 0, 0, 0);
            }
            if constexpr (V == 1) {
                asm volatile("" :: "v"(acc0), "v"(acc1));   // keep live, no reduce
                vmax = (mh == 0) ? acc0[0] : fmaxf(vmax, acc1[0]);
            } else {
                if (mh == 0) {
                    float a = fmaxf(fmaxf(acc0[0], acc0[1]), fmaxf(acc0[2], acc0[3]));
                    float c = fmaxf(fmaxf(acc1[0], acc1[1]), fmaxf(acc1[2], acc1[3]));
                    vmax = fmaxf(a, c);
                } else {
                    float c = fmaxf(fmaxf(acc0[0], acc0[1]), fmaxf(acc0[2], acc0[3]));
                    float d = (lhi == 0) ? acc1[0] : -3e38f;
                    vmax = fmaxf(vmax, fmaxf(c, d));
                }
            }
        }
        vals[wave][j][lane] = vmax;
    };

    if constexpr (V == 2) {
        bf16x8 T[4];
        loadT(T, 0);
        #pragma unroll 1
        for (int j = 0; j < 25; j++) {
            #pragma unroll
            for (int k = 0; k < 4; k++) asm volatile("" : "+v"(T[k]));  // no CSE
            compute(T, j);
        }
    } else {
        bf16x8 A[4], B[4];
        loadT(A, 0);
        #pragma unroll 1
        for (int jj = 0; jj < 12; jj++) {
            loadT(B, 2 * jj + 1);
            compute(A, 2 * jj);
            loadT(A, 2 * jj + 2);
            compute(B, 2 * jj + 1);
        }
        compute(A, 24);
    }
    __syncthreads();

    // Epilogue: max over 4 lane-groups + length-25 sum + scale
    if (tid < WAVES * CH_T) {
        int g  = tid >> 4;
        int tl = tid & 15;
        float s = 0.f;
        #pragma unroll
        for (int l = 0; l < 25; l++) {
            int row = tl * 25 + l;
            int j = row >> 4;
            int r = row & 15;
            float m0 = fmaxf(vals[g][j][r],      vals[g][j][r + 16]);
            float m1 = fmaxf(vals[g][j][r + 32], vals[g][j][r + 48]);
            s += fmaxf(m0, m1);
        }
        int t = tq * CH_T + tl;
        int i = ig * WAVES + g;
        float val = s / (float)text_length[t] * expf(logit_scale[0]);
        out[(size_t)i * NT + t] = val;                      // logits_per_image [I,T]
        out[(size_t)NI * NT + (size_t)t * NI + i] = val;    // logits_per_text  [T,I]
    }
}

extern "C" void kernel_launch(void* const* d_in, const int* in_sizes, int n_in,
                              void* d_out, int out_size, void* d_ws, size_t ws_size,
                              hipStream_t stream)
{
    const float* img  = (const float*)d_in[0];   // [256,128,7,7]
    const float* emb  = (const float*)d_in[1];   // [10000,128]
    const float* ls   = (const float*)d_in[2];   // scalar
    const int*   text = (const int*)d_in[3];     // [256,25]
    const int*   tlen = (const int*)d_in[4];     // [256]
    float* out = (float*)d_out;

    char* ws = (char*)d_ws;
    __hip_bfloat16* tf3  = (__hip_bfloat16*)ws;                 // 1,638,400 B
    __hip_bfloat16* P2   = (__hip_bfloat16*)(ws + 1638400);     // 4,194,304 B
    __hip_bfloat16* dtf3 = (__hip_bfloat16*)(ws + 6291456);     // probe dummies
    __hip_bfloat16* dP2  = (__hip_bfloat16*)(ws + 8388608);
    float* dout0 = (float*)(ws + 16777216);
    float* dout1 = (float*)(ws + 16777216 + 1048576);
    float* dout2 = (float*)(ws + 16777216 + 2097152);
    float* dout3 = (float*)(ws + 16777216 + 3145728);

    // ---- real path (output-producing, identical to round 9) ----
    prep_kernel<<<400 + NI, 256, 0, stream>>>(emb, text, img, tf3, P2);
    match_t<0><<<512, 512, 0, stream>>>(tf3, P2, tlen, ls, out);

    // ---- measurement battery (oversized grids so rocprof top-5 shows them) ----
    prep_probe<<<656 * 16, 256, 0, stream>>>(emb, text, img, dtf3, dP2);
    match_t<0><<<512 * 8, 512, 0, stream>>>(tf3, P2, tlen, ls, dout0);
    match_t<1><<<512 * 8, 512, 0, stream>>>(tf3, P2, tlen, ls, dout1);
    match_t<2><<<512 * 8, 512, 0, stream>>>(tf3, P2, tlen, ls, dout2);
    match_t<3><<<512 * 8, 512, 0, stream>>>(tf3, P2, tlen, ls, dout3);
}

// Round 11
// 32.094 us; speedup vs baseline: 18.2948x; 18.2948x over previous
//
#include <hip/hip_runtime.h>
#include <hip/hip_bf16.h>
#include <stdint.h>

#define NI 256
#define NT 256
#define NL 25
#define NE 128
#define NHW 49
#define NTL (NT*NL)   // 6400

#define WAVES 8            // waves (=images) per match WG
#define CH_T 16            // texts per chunk
#define CH_TILES 25        // 16-row B tiles per chunk

typedef __attribute__((ext_vector_type(8))) short bf16x8;
typedef __attribute__((ext_vector_type(4))) float f32x4;

__device__ __forceinline__ short f2bf(float x) {
    __hip_bfloat16 h = __float2bfloat16(x);
    return *reinterpret_cast<short*>(&h);
}

// ---- Prep ----
// blocks 0..399: tf3 in B-fragment order (unchanged from r9).
// blocks 400..655: P2, 3 m-tiles/image (patches 0..47, all real, no pad):
//   P2[i][m*4+k][lane] = patch m*16+(lane&15), elems k*32+(lane>>4)*8..+8.
// blocks 656..687: P48[group g][k][lane]: row lr<8 = patch 48 of image
//   g*8+lr, elems k*32+(lane>>4)*8..+8; rows 8..15 zero.
__global__ __launch_bounds__(256) void prep_kernel(
    const float* __restrict__ emb, const int* __restrict__ text,
    const float* __restrict__ img,
    __hip_bfloat16* __restrict__ tf3, __hip_bfloat16* __restrict__ P2,
    __hip_bfloat16* __restrict__ P48)
{
    __shared__ float tile[NE * NHW];
    int bid = blockIdx.x;

    if (bid < 400) {
        int idx  = bid * 256 + threadIdx.x;   // 16B chunk id, 102400 total
        int lane = idx & 63;
        int k    = (idx >> 6) & 3;
        int j    = idx >> 8;                  // global 16-row tile 0..399
        int lr = lane & 15, lhi = lane >> 4;
        int row = j * 16 + lr;
        int tok = text[row];
        const float* src = emb + (size_t)tok * NE + k * 32 + lhi * 8;
        float4 a = *reinterpret_cast<const float4*>(src);
        float4 b = *reinterpret_cast<const float4*>(src + 4);
        bf16x8 o;
        o[0] = f2bf(a.x); o[1] = f2bf(a.y); o[2] = f2bf(a.z); o[3] = f2bf(a.w);
        o[4] = f2bf(b.x); o[5] = f2bf(b.y); o[6] = f2bf(b.z); o[7] = f2bf(b.w);
        *reinterpret_cast<bf16x8*>(tf3 + (size_t)idx * 8) = o;
    } else if (bid < 656) {
        int i = bid - 400;
        const float4* src4 = reinterpret_cast<const float4*>(img + (size_t)i * NE * NHW);
        float4* tile4 = reinterpret_cast<float4*>(tile);
        for (int idx = threadIdx.x; idx < NE * NHW / 4; idx += 256) tile4[idx] = src4[idx];
        __syncthreads();
        for (int idx = threadIdx.x; idx < 768; idx += 256) {   // (mk<12, lane)
            int mk = idx >> 6, lane = idx & 63;
            int m = mk >> 2, k = mk & 3;
            int lr = lane & 15, lhi = lane >> 4;
            int p = m * 16 + lr;                                // 0..47, all real
            bf16x8 o;
            #pragma unroll
            for (int jj = 0; jj < 8; jj++)
                o[jj] = f2bf(tile[(k * 32 + lhi * 8 + jj) * NHW + p]);
            *reinterpret_cast<bf16x8*>(P2 + ((size_t)(i * 12 + mk) * 64 + lane) * 8) = o;
        }
    } else {
        int g = bid - 656;                    // image group 0..31
        int tid = threadIdx.x;
        int k = tid >> 6, lane = tid & 63;
        int lr = lane & 15, lhi = lane >> 4;
        bf16x8 o = {};
        if (lr < 8) {
            const float* s = img + (size_t)(g * 8 + lr) * NE * NHW + 48;
            #pragma unroll
            for (int jj = 0; jj < 8; jj++)
                o[jj] = f2bf(s[(size_t)(k * 32 + lhi * 8 + jj) * NHW]);
        }
        *reinterpret_cast<bf16x8*>(P48 + ((size_t)(g * 4 + k) * 64 + lane) * 8) = o;
    }
}

// ---- Match: register-resident MFMA GEMM + packed patch-48 duty tile ----
// 512 WGs = 32 image-groups (8 images) x 16 text-chunks; wave = 1 image,
// 3 m-tiles (patches 0..47, no padding waste). Patch 48 of all 8 images is
// computed by the duty wave ((j&7)==wave) via one packed 16x16 tile (A rows
// = images) into vals48. Shared zero-C kills acc-init movs; reduce is
// max3-shaped. Register budget ~112 combined -> 2 WGs/CU at 1x grid.
__global__ __launch_bounds__(512, 4) void match_kernel(
    const __hip_bfloat16* __restrict__ tf3,
    const __hip_bfloat16* __restrict__ P2,
    const __hip_bfloat16* __restrict__ P48,
    const int* __restrict__ text_length,
    const float* __restrict__ logit_scale,
    float* __restrict__ out)
{
    __shared__ float vals[WAVES][CH_TILES][64];   // per-lane 12-patch max
    __shared__ float vals48[CH_TILES][128];       // [j][img*16+textcol] patch-48 sims

    const int ig   = blockIdx.x & 31;    // image group (8 images)
    const int tq   = blockIdx.x >> 5;    // text chunk (16 texts = 25 tiles)
    const int tid  = threadIdx.x;
    const int wave = tid >> 6;
    const int lane = tid & 63;
    const int lr   = lane & 15;
    const int lhi  = lane >> 4;

    // pfrag: 12 coalesced 1KB loads from fragment-order P2, pinned resident
    const int img = ig * WAVES + wave;
    const bf16x8* p2 = reinterpret_cast<const bf16x8*>(P2) + (size_t)img * 12 * 64 + lane;
    bf16x8 pfrag[3][4];
    #pragma unroll
    for (int m = 0; m < 3; m++)
        #pragma unroll
        for (int k = 0; k < 4; k++)
            pfrag[m][k] = p2[(m * 4 + k) * 64];
    #pragma unroll
    for (int m = 0; m < 3; m++)
        #pragma unroll
        for (int k = 0; k < 4; k++)
            asm volatile("" : "+v"(pfrag[m][k]));

    // duty-tile A-frags: loaded from L1 inside the duty branch (no regs held)
    const bf16x8* p48 = reinterpret_cast<const bf16x8*>(P48) + (size_t)ig * 4 * 64 + lane;

    // shared zero C-operand (init once; MFMA dest != C, so never re-zeroed)
    f32x4 zeroC = (f32x4){0.f, 0.f, 0.f, 0.f};
    asm volatile("" : "+v"(zeroC));

    // B-fragment stream base: tile j at +j*4096, k at +k*1024, lane*16
    const char* tb = (const char*)tf3 + (size_t)tq * CH_TILES * 4096 + lane * 16;

    auto loadT = [&](bf16x8* T, int j) {
        #pragma unroll
        for (int k = 0; k < 4; k++)
            T[k] = *reinterpret_cast<const bf16x8*>(tb + j * 4096 + k * 1024);
    };

    auto compute = [&](const bf16x8* T, int j) {
        __builtin_amdgcn_s_setprio(1);
        f32x4 a0 = __builtin_amdgcn_mfma_f32_16x16x32_bf16(pfrag[0][0], T[0], zeroC, 0, 0, 0);
        f32x4 a1 = __builtin_amdgcn_mfma_f32_16x16x32_bf16(pfrag[1][0], T[0], zeroC, 0, 0, 0);
        f32x4 a2 = __builtin_amdgcn_mfma_f32_16x16x32_bf16(pfrag[2][0], T[0], zeroC, 0, 0, 0);
        #pragma unroll
        for (int k = 1; k < 4; k++) {
            a0 = __builtin_amdgcn_mfma_f32_16x16x32_bf16(pfrag[0][k], T[k], a0, 0, 0, 0);
            a1 = __builtin_amdgcn_mfma_f32_16x16x32_bf16(pfrag[1][k], T[k], a1, 0, 0, 0);
            a2 = __builtin_amdgcn_mfma_f32_16x16x32_bf16(pfrag[2][k], T[k], a2, 0, 0, 0);
        }
        if ((j & 7) == wave) {
            // packed patch-48 tile: A rows = this group's 8 images (L1-hot)
            f32x4 a48 = __builtin_amdgcn_mfma_f32_16x16x32_bf16(p48[0],   T[0], zeroC, 0, 0, 0);
            a48 = __builtin_amdgcn_mfma_f32_16x16x32_bf16(p48[64],  T[1], a48, 0, 0, 0);
            a48 = __builtin_amdgcn_mfma_f32_16x16x32_bf16(p48[128], T[2], a48, 0, 0, 0);
            a48 = __builtin_amdgcn_mfma_f32_16x16x32_bf16(p48[192], T[3], a48, 0, 0, 0);
            __builtin_amdgcn_s_setprio(0);
            if (lhi < 2) {
                #pragma unroll
                for (int r = 0; r < 4; r++)
                    vals48[j][(lhi * 4 + r) * 16 + lr] = a48[r];   // row=image, col=text
            }
        } else {
            __builtin_amdgcn_s_setprio(0);
        }
        // per-lane max over its 12 patches (m*16 + lhi*4 + r), all real
        float r1 = fmaxf(fmaxf(a0[0], a0[1]), a0[2]);
        float r2 = fmaxf(fmaxf(a0[3], a1[0]), a1[1]);
        float r3 = fmaxf(fmaxf(a1[2], a1[3]), a2[0]);
        float r4 = fmaxf(fmaxf(a2[1], a2[2]), a2[3]);
        vals[wave][j][lane] = fmaxf(fmaxf(fmaxf(r1, r2), r3), r4);
    };

    bf16x8 A[4], B[4];
    loadT(A, 0);
    #pragma unroll 1
    for (int jj = 0; jj < 12; jj++) {
        loadT(B, 2 * jj + 1);
        compute(A, 2 * jj);
        loadT(A, 2 * jj + 2);
        compute(B, 2 * jj + 1);
    }
    compute(A, 24);
    __syncthreads();

    // Epilogue: max over 4 lane-groups + patch-48 + length-25 sum + scale.
    if (tid < WAVES * CH_T) {
        int g  = tid >> 4;
        int tl = tid & 15;
        float s = 0.f;
        #pragma unroll
        for (int l = 0; l < 25; l++) {
            int row = tl * 25 + l;          // text row within chunk, 0..399
            int j = row >> 4;
            int r = row & 15;
            float m0 = fmaxf(vals[g][j][r],      vals[g][j][r + 16]);
            float m1 = fmaxf(vals[g][j][r + 32], vals[g][j][r + 48]);
            float v48 = vals48[j][g * 16 + r];
            s += fmaxf(fmaxf(m0, m1), v48);
        }
        int t = tq * CH_T + tl;
        int i = ig * WAVES + g;
        float val = s / (float)text_length[t] * expf(logit_scale[0]);
        out[(size_t)i * NT + t] = val;                      // logits_per_image [I,T]
        out[(size_t)NI * NT + (size_t)t * NI + i] = val;    // logits_per_text  [T,I]
    }
}

extern "C" void kernel_launch(void* const* d_in, const int* in_sizes, int n_in,
                              void* d_out, int out_size, void* d_ws, size_t ws_size,
                              hipStream_t stream)
{
    const float* img  = (const float*)d_in[0];   // [256,128,7,7]
    const float* emb  = (const float*)d_in[1];   // [10000,128]
    const float* ls   = (const float*)d_in[2];   // scalar
    const int*   text = (const int*)d_in[3];     // [256,25]
    const int*   tlen = (const int*)d_in[4];     // [256]
    float* out = (float*)d_out;

    char* ws = (char*)d_ws;
    __hip_bfloat16* tf3 = (__hip_bfloat16*)ws;                 // 1,638,400 B
    __hip_bfloat16* P2  = (__hip_bfloat16*)(ws + 1638400);     // 3,145,728 B
    __hip_bfloat16* P48 = (__hip_bfloat16*)(ws + 4784128);     //   131,072 B

    prep_kernel<<<688, 256, 0, stream>>>(emb, text, img, tf3, P2, P48);
    match_kernel<<<512, 512, 0, stream>>>(tf3, P2, P48, tlen, ls, out);
}

// Round 12
// 23.089 us; speedup vs baseline: 25.4294x; 1.3900x over previous
//
#include <hip/hip_runtime.h>
#include <hip/hip_bf16.h>
#include <stdint.h>

#define NI 256
#define NT 256
#define NL 25
#define NE 128
#define NHW 49
#define NTL (NT*NL)   // 6400

#define WAVES 8            // waves (=images) per match WG
#define CH_T 16            // texts per chunk
#define CH_TILES 25        // 16-row B tiles per chunk

typedef __attribute__((ext_vector_type(4))) int i32x4;

__device__ __forceinline__ int pack4(int q0, int q1, int q2, int q3) {
    return (q0 & 255) | ((q1 & 255) << 8) | ((q2 & 255) << 16) | ((q3 & 255) << 24);
}

// ---- Prep ----
// blocks 0..399 (text tile j): per-word i8 quant + B-fragment order (K=64):
//   chunk c=(j*2+kh)*64+lane (16B): byte b = q(emb[text[j*16+lr]][kh*64+lhi*16+b]),
//   scale tfs[row] = rowmax/127 (0 for zero rows -> sims exactly 0).
// blocks 400..655 (image i): per-image i8 quant. P2 A-fragments:
//   chunk (i*6+m*2+kh)*64+lane: byte b = q(img patch m*16+lr, elem kh*64+lhi*16+b).
//   Also writes its row of the packed patch-48 duty tile P48 and pscale[i].
__global__ __launch_bounds__(256) void prep_kernel(
    const float* __restrict__ emb, const int* __restrict__ text,
    const float* __restrict__ img,
    char* __restrict__ tf3, char* __restrict__ P2, char* __restrict__ P48,
    float* __restrict__ tfs, float* __restrict__ pscale)
{
    __shared__ float tile[NE * NHW];
    __shared__ float red[256];
    const int bid = blockIdx.x;
    const int tid = threadIdx.x;

    if (bid < 400) {
        // ---- text tile: 16 rows x 128 elems; thread = (row r, sub) ----
        int r   = tid >> 4;
        int sub = tid & 15;
        int row = bid * 16 + r;
        int tok = text[row];
        const float4* e4 = reinterpret_cast<const float4*>(emb + (size_t)tok * NE + sub * 8);
        float4 f0 = e4[0], f1 = e4[1];
        float m = fmaxf(fmaxf(fmaxf(fabsf(f0.x), fabsf(f0.y)), fmaxf(fabsf(f0.z), fabsf(f0.w))),
                        fmaxf(fmaxf(fabsf(f1.x), fabsf(f1.y)), fmaxf(fabsf(f1.z), fabsf(f1.w))));
        // row max across the 16 threads of this row (lanes share a 16-group)
        m = fmaxf(m, __shfl_xor(m, 1));
        m = fmaxf(m, __shfl_xor(m, 2));
        m = fmaxf(m, __shfl_xor(m, 4));
        m = fmaxf(m, __shfl_xor(m, 8));
        float s = (m > 0.f) ? 127.f / m : 0.f;
        if (sub == 0) tfs[row] = m / 127.f;
        int q0 = __float2int_rn(f0.x * s), q1 = __float2int_rn(f0.y * s);
        int q2 = __float2int_rn(f0.z * s), q3 = __float2int_rn(f0.w * s);
        int q4 = __float2int_rn(f1.x * s), q5 = __float2int_rn(f1.y * s);
        int q6 = __float2int_rn(f1.z * s), q7 = __float2int_rn(f1.w * s);
        int2 o = make_int2(pack4(q0, q1, q2, q3), pack4(q4, q5, q6, q7));
        int kh  = sub >> 3;
        int lhi = (sub >> 1) & 3;
        size_t addr = ((size_t)(bid * 2 + kh) * 64 + lhi * 16 + r) * 16 + (sub & 1) * 8;
        *reinterpret_cast<int2*>(tf3 + addr) = o;
    } else {
        // ---- image block ----
        int i = bid - 400;
        const float4* src4 = reinterpret_cast<const float4*>(img + (size_t)i * NE * NHW);
        float4* tile4 = reinterpret_cast<float4*>(tile);
        for (int idx = tid; idx < NE * NHW / 4; idx += 256) tile4[idx] = src4[idx];
        __syncthreads();
        float lm = 0.f;
        for (int idx = tid; idx < NE * NHW; idx += 256) lm = fmaxf(lm, fabsf(tile[idx]));
        red[tid] = lm;
        __syncthreads();
        #pragma unroll
        for (int st = 128; st > 0; st >>= 1) {
            if (tid < st) red[tid] = fmaxf(red[tid], red[tid + st]);
            __syncthreads();
        }
        float pmax = red[0];
        float s = (pmax > 0.f) ? 127.f / pmax : 0.f;
        if (tid == 0) pscale[i] = pmax / 127.f;

        // P2 fragments: 6 frags (m<3, kh<2) x 64 lanes, 16B each
        for (int idx = tid; idx < 384; idx += 256) {
            int f = idx >> 6, lane = idx & 63;
            int mt = f >> 1, kh = f & 1;
            int lr = lane & 15, lhi = lane >> 4;
            int p = mt * 16 + lr;              // 0..47, all real
            int d[4];
            #pragma unroll
            for (int w = 0; w < 4; w++) {
                int e = kh * 64 + lhi * 16 + w * 4;
                d[w] = pack4(__float2int_rn(tile[(e + 0) * NHW + p] * s),
                             __float2int_rn(tile[(e + 1) * NHW + p] * s),
                             __float2int_rn(tile[(e + 2) * NHW + p] * s),
                             __float2int_rn(tile[(e + 3) * NHW + p] * s));
            }
            i32x4 o = { d[0], d[1], d[2], d[3] };
            *reinterpret_cast<i32x4*>(P2 + ((size_t)(i * 6 + f) * 64 + lane) * 16) = o;
        }
        // duty-tile row: patch 48 of this image -> P48 group g=i>>3, row lr0=i&7
        if (tid < 8) {
            int kh = tid & 1, lhi = (tid >> 1) & 3;
            int g = i >> 3, lr0 = i & 7;
            int d[4];
            #pragma unroll
            for (int w = 0; w < 4; w++) {
                int e = kh * 64 + lhi * 16 + w * 4;
                d[w] = pack4(__float2int_rn(tile[(e + 0) * NHW + 48] * s),
                             __float2int_rn(tile[(e + 1) * NHW + 48] * s),
                             __float2int_rn(tile[(e + 2) * NHW + 48] * s),
                             __float2int_rn(tile[(e + 3) * NHW + 48] * s));
            }
            i32x4 o = { d[0], d[1], d[2], d[3] };
            *reinterpret_cast<i32x4*>(P48 + ((size_t)(g * 2 + kh) * 64 + lhi * 16 + lr0) * 16) = o;
        }
    }
}

// ---- Match: i8 MFMA GEMM (swapped operands) + int max + descaled sum ----
// 512 WGs = 32 image-groups (8 images) x 16 text-chunks; wave = 1 image.
// 3 m-tiles x 2 K-halves = 6 mfma_i32_16x16x64_i8 per 16-text tile (+duty).
// Max over patches in int (per-(image,word) positive scale commutes);
// descale once per (t,l) in the epilogue.
__global__ __launch_bounds__(512, 4) void match_kernel(
    const char* __restrict__ tf3,
    const char* __restrict__ P2,
    const char* __restrict__ P48,
    const float* __restrict__ tfs,
    const float* __restrict__ pscale,
    const int* __restrict__ text_length,
    const float* __restrict__ logit_scale,
    float* __restrict__ out)
{
    __shared__ int vals[WAVES][CH_TILES][64];   // per-lane 12-patch int max
    __shared__ int vals48[CH_TILES][128];       // [j][imgrow*16+textcol] patch-48 i32

    const int ig   = blockIdx.x & 31;    // image group (8 images)
    const int tq   = blockIdx.x >> 5;    // text chunk (16 texts = 25 tiles)
    const int tid  = threadIdx.x;
    const int wave = tid >> 6;
    const int lane = tid & 63;
    const int lr   = lane & 15;
    const int lhi  = lane >> 4;

    // pfrag: 6 coalesced 1KB loads from fragment-order P2, pinned resident
    const int img = ig * WAVES + wave;
    const i32x4* p2 = reinterpret_cast<const i32x4*>(P2) + (size_t)img * 6 * 64 + lane;
    i32x4 pf[6];
    #pragma unroll
    for (int f = 0; f < 6; f++) pf[f] = p2[f * 64];
    #pragma unroll
    for (int f = 0; f < 6; f++) asm volatile("" : "+v"(pf[f]));

    const i32x4* p48 = reinterpret_cast<const i32x4*>(P48) + (size_t)ig * 2 * 64 + lane;

    i32x4 zc = { 0, 0, 0, 0 };
    asm volatile("" : "+v"(zc));

    // B stream: tile jl at +jl*2048, K-half kh at +kh*1024, lane*16
    const char* tb = tf3 + (size_t)tq * CH_TILES * 2048 + lane * 16;

    auto loadT = [&](i32x4* T, int jl) {
        T[0] = *reinterpret_cast<const i32x4*>(tb + jl * 2048);
        T[1] = *reinterpret_cast<const i32x4*>(tb + jl * 2048 + 1024);
    };

    auto imax = [](int a, int b) { return a > b ? a : b; };

    auto compute = [&](const i32x4* T, int jl) {
        __builtin_amdgcn_s_setprio(1);
        i32x4 a0 = __builtin_amdgcn_mfma_i32_16x16x64_i8(pf[0], T[0], zc, 0, 0, 0);
        i32x4 a1 = __builtin_amdgcn_mfma_i32_16x16x64_i8(pf[2], T[0], zc, 0, 0, 0);
        i32x4 a2 = __builtin_amdgcn_mfma_i32_16x16x64_i8(pf[4], T[0], zc, 0, 0, 0);
        a0 = __builtin_amdgcn_mfma_i32_16x16x64_i8(pf[1], T[1], a0, 0, 0, 0);
        a1 = __builtin_amdgcn_mfma_i32_16x16x64_i8(pf[3], T[1], a1, 0, 0, 0);
        a2 = __builtin_amdgcn_mfma_i32_16x16x64_i8(pf[5], T[1], a2, 0, 0, 0);
        if ((jl & 7) == wave) {
            // packed patch-48 tile: A rows = this group's 8 images (L1-hot)
            i32x4 d = __builtin_amdgcn_mfma_i32_16x16x64_i8(p48[0],  T[0], zc, 0, 0, 0);
            d = __builtin_amdgcn_mfma_i32_16x16x64_i8(p48[64], T[1], d, 0, 0, 0);
            __builtin_amdgcn_s_setprio(0);
            if (lhi < 2) {
                #pragma unroll
                for (int r = 0; r < 4; r++)
                    vals48[jl][(lhi * 4 + r) * 16 + lr] = d[r];   // row=image, col=text
            }
        } else {
            __builtin_amdgcn_s_setprio(0);
        }
        // per-lane int max over its 12 patches (same image, same text col)
        int r1 = imax(imax(a0[0], a0[1]), a0[2]);
        int r2 = imax(imax(a0[3], a1[0]), a1[1]);
        int r3 = imax(imax(a1[2], a1[3]), a2[0]);
        int r4 = imax(imax(a2[1], a2[2]), a2[3]);
        vals[wave][jl][lane] = imax(imax(r1, r2), imax(r3, r4));
    };

    i32x4 A[2], B[2];
    loadT(A, 0);
    #pragma unroll 1
    for (int jj = 0; jj < 12; jj++) {
        loadT(B, 2 * jj + 1);
        compute(A, 2 * jj);
        loadT(A, 2 * jj + 2);
        compute(B, 2 * jj + 1);
    }
    compute(A, 24);
    __syncthreads();

    // Epilogue: int max over 4 lane-groups + duty row, descale, sum, scale.
    if (tid < WAVES * CH_T) {
        int g  = tid >> 4;
        int tl = tid & 15;
        float simg = pscale[ig * WAVES + g];
        const float* tf_s = tfs + tq * 400;
        float s = 0.f;
        #pragma unroll
        for (int l = 0; l < 25; l++) {
            int row = tl * 25 + l;          // text row within chunk, 0..399
            int j = row >> 4;
            int r = row & 15;
            int m0 = imax(vals[g][j][r],      vals[g][j][r + 16]);
            int m1 = imax(vals[g][j][r + 32], vals[g][j][r + 48]);
            int mm = imax(imax(m0, m1), vals48[j][g * 16 + r]);
            s += (float)mm * tf_s[row];
        }
        int t = tq * CH_T + tl;
        int i = ig * WAVES + g;
        float val = s * simg / (float)text_length[t] * expf(logit_scale[0]);
        out[(size_t)i * NT + t] = val;                      // logits_per_image [I,T]
        out[(size_t)NI * NT + (size_t)t * NI + i] = val;    // logits_per_text  [T,I]
    }
}

extern "C" void kernel_launch(void* const* d_in, const int* in_sizes, int n_in,
                              void* d_out, int out_size, void* d_ws, size_t ws_size,
                              hipStream_t stream)
{
    const float* img  = (const float*)d_in[0];   // [256,128,7,7]
    const float* emb  = (const float*)d_in[1];   // [10000,128]
    const float* ls   = (const float*)d_in[2];   // scalar
    const int*   text = (const int*)d_in[3];     // [256,25]
    const int*   tlen = (const int*)d_in[4];     // [256]
    float* out = (float*)d_out;

    char* ws = (char*)d_ws;
    char*  tf3    = ws;                          //   819,200 B (i8 B-fragments)
    char*  P2     = ws + 819200;                 // 1,572,864 B (i8 A-fragments)
    char*  P48    = ws + 2392064;                //    65,536 B (packed patch-48)
    float* tfs    = (float*)(ws + 2457600);      //    25,600 B (per-word scales)
    float* pscale = (float*)(ws + 2483200);      //     1,024 B (per-image scales)

    prep_kernel<<<656, 256, 0, stream>>>(emb, text, img, tf3, P2, P48, tfs, pscale);
    match_kernel<<<512, 512, 0, stream>>>(tf3, P2, P48, tfs, pscale, tlen, ls, out);
}